// Round 11
// baseline (265.102 us; speedup 1.0000x reference)
//
#include <hip/hip_runtime.h>
#include <hip/hip_fp16.h>

#define N_NODES 50000
#define N_EDGES 1000000
#define D 64
#define L 3
#define BN_EPS 1e-5f
#define NB_SCAN ((N_NODES + 255) / 256)   // 196 blocks of 256
#define AGG_BLOCKS ((N_NODES + 31) / 32)  // 1563: 16 groups/block, 2 nodes/group
#define NXCD 8
#define BN_XSTRIDE (L * 2 * D)            // per-XCD bnsum replica stride (floats)

// ---------------------------------------------------------------- helpers
__device__ inline int get_xcc() {
    int x;
    asm volatile("s_getreg_b32 %0, hwreg(HW_REG_XCC_ID)" : "=s"(x));
    return x & (NXCD - 1);
}

// BN affine from per-XCD replicated sums.
__device__ inline void bn_affine8(const float* __restrict__ bnsum_l,
                                  const float* __restrict__ gamma,
                                  const float* __restrict__ beta,
                                  int c, float& sc, float& sh) {
    float s1 = 0.f, s2 = 0.f;
#pragma unroll
    for (int x = 0; x < NXCD; x++) {
        s1 += bnsum_l[(size_t)x * BN_XSTRIDE + c];
        s2 += bnsum_l[(size_t)x * BN_XSTRIDE + D + c];
    }
    float mean = s1 * (1.f / N_NODES);
    float var = fmaf(-mean, mean, s2 * (1.f / N_NODES));
    float inv = rsqrtf(var + BN_EPS);
    sc = gamma[c] * inv;
    sh = fmaf(-mean, sc, beta[c]);
}

__device__ inline float unpack_w(unsigned int m) {
    __half_raw hr;
    hr.x = (unsigned short)(m & 0xffffu);
    __half h = *reinterpret_cast<__half*>(&hr);
    return __half2float(h);
}

__device__ inline float2 unpack_x2(unsigned int q) {
    __half2 h2 = *reinterpret_cast<__half2*>(&q);
    return __half22float2(h2);
}

__device__ inline float2 ntload_f2(const float2* p) {
    unsigned long long u = __builtin_nontemporal_load((const unsigned long long*)p);
    float2 r;
    r.x = __uint_as_float((unsigned int)(u & 0xffffffffull));
    r.y = __uint_as_float((unsigned int)(u >> 32));
    return r;
}

__device__ inline void ntstore_f2(float2* p, float2 v) {
    unsigned long long u =
        ((unsigned long long)__float_as_uint(v.y) << 32) | (unsigned long long)__float_as_uint(v.x);
    __builtin_nontemporal_store(u, (unsigned long long*)p);
}

// ---------------------------------------------------------------- init
__global__ void init_kernel(int* __restrict__ counts8, float* __restrict__ bnsum8) {
    int i = blockIdx.x * blockDim.x + threadIdx.x;
    int stride = gridDim.x * blockDim.x;
    for (int j = i; j < NXCD * N_NODES; j += stride) counts8[j] = 0;
    for (int j = i; j < NXCD * BN_XSTRIDE; j += stride) bnsum8[j] = 0.f;
}

// ---------------------------------------------------------------- CSR build
// Per-XCD histograms: atomics stay local to one XCD's L2.
__global__ void count_kernel(const int* __restrict__ dst, int* __restrict__ counts8,
                             unsigned short* __restrict__ rankx) {
    int xcd = get_xcc();
    int* mycnt = counts8 + (size_t)xcd * N_NODES;
    int i = blockIdx.x * blockDim.x + threadIdx.x;
    int stride = gridDim.x * blockDim.x;
    for (int e = i; e < N_EDGES; e += stride) {
        int r = atomicAdd(&mycnt[dst[e]], 1);
        rankx[e] = (unsigned short)(r | (xcd << 13));
    }
}

__global__ __launch_bounds__(256) void scanA_kernel(const int* __restrict__ counts8,
                                                    int* __restrict__ counts,
                                                    int* __restrict__ blocksum) {
    __shared__ int buf[256];
    int t = threadIdx.x, b = blockIdx.x;
    int i = b * 256 + t;
    int v = 0;
    if (i < N_NODES) {
#pragma unroll
        for (int x = 0; x < NXCD; x++) v += counts8[(size_t)x * N_NODES + i];
        counts[i] = v;
    }
    buf[t] = v;
    __syncthreads();
    for (int off = 128; off > 0; off >>= 1) {
        if (t < off) buf[t] += buf[t + off];
        __syncthreads();
    }
    if (t == 0) blocksum[b] = buf[0];
}

__global__ __launch_bounds__(256) void scanB_kernel(const int* __restrict__ blocksum,
                                                    int* __restrict__ blockoff,
                                                    int* __restrict__ row_ptr) {
    __shared__ int buf[256];
    int t = threadIdx.x;
    int v = (t < NB_SCAN) ? blocksum[t] : 0;
    buf[t] = v;
    __syncthreads();
    for (int off = 1; off < 256; off <<= 1) {
        int u = (t >= off) ? buf[t - off] : 0;
        __syncthreads();
        buf[t] += u;
        __syncthreads();
    }
    if (t < NB_SCAN) blockoff[t] = buf[t] - v;  // exclusive
    if (t == NB_SCAN - 1) row_ptr[N_NODES] = buf[t];
}

// phase C fused with offs8.
__global__ __launch_bounds__(256) void scanC_kernel(const int* __restrict__ counts,
                                                    const int* __restrict__ counts8,
                                                    const int* __restrict__ blockoff,
                                                    int* __restrict__ row_ptr,
                                                    int* __restrict__ offs8) {
    __shared__ int buf[256];
    int t = threadIdx.x, b = blockIdx.x;
    int i = b * 256 + t;
    int v = (i < N_NODES) ? counts[i] : 0;
    buf[t] = v;
    __syncthreads();
    for (int off = 1; off < 256; off <<= 1) {
        int u = (t >= off) ? buf[t - off] : 0;
        __syncthreads();
        buf[t] += u;
        __syncthreads();
    }
    if (i < N_NODES) {
        int base = blockoff[b] + buf[t] - v;
        row_ptr[i] = base;
#pragma unroll
        for (int x = 0; x < NXCD; x++) {
            offs8[(size_t)x * N_NODES + i] = base;
            base += counts8[(size_t)x * N_NODES + i];
        }
    }
}

__global__ void fill_kernel(const int* __restrict__ src, const int* __restrict__ dst,
                            const float* __restrict__ w,
                            const unsigned short* __restrict__ rankx,
                            const int* __restrict__ offs8,
                            unsigned int* __restrict__ em) {
    int i = blockIdx.x * blockDim.x + threadIdx.x;
    int stride = gridDim.x * blockDim.x;
    for (int e = i; e < N_EDGES; e += stride) {
        int d = dst[e];
        unsigned rx = rankx[e];
        int p = offs8[(size_t)(rx >> 13) * N_NODES + d] + (int)(rx & 0x1fffu);
        __half h = __float2half_rn(w[e]);
        unsigned short wb = reinterpret_cast<__half_raw*>(&h)->x;
        em[p] = ((unsigned int)src[e] << 16) | (unsigned int)wb;
    }
}

// ---------------------------------------------------------------- GEMM
// Output fp16 in two feature-halves: xw2[half][v][32] (each half = 3.2 MB).
__global__ __launch_bounds__(256) void gemm_kernel(const float* __restrict__ hraw,
                                                   const float* __restrict__ bnsum_p,
                                                   const float* __restrict__ gamma_p,
                                                   const float* __restrict__ beta_p,
                                                   const float* __restrict__ Wl,
                                                   __half* __restrict__ xw2) {
    __shared__ float aff[2][D];
    int tid = threadIdx.x, lane = tid & 63, wave = tid >> 6;
    if (tid < D) {
        float sc = 1.f, sh = 0.f;
        if (bnsum_p) bn_affine8(bnsum_p, gamma_p, beta_p, tid, sc, sh);
        aff[0][tid] = sc;
        aff[1][tid] = sh;
    }
    __syncthreads();
    float Wreg[D];
    float biasc = 0.f;
#pragma unroll
    for (int k = 0; k < D; k++) {
        float wkc = Wl[k * D + lane];   // lane = output column c
        biasc = fmaf(aff[1][k], wkc, biasc);
        Wreg[k] = wkc * aff[0][k];
    }
    int halfid = lane >> 5, fl2 = lane & 31;
    __half* dstp = xw2 + (size_t)halfid * N_NODES * 32;
    int gw = blockIdx.x * 4 + wave, nw = gridDim.x * 4;
    for (int v = gw; v < N_NODES; v += nw) {
        const float* hp = hraw + (size_t)__builtin_amdgcn_readfirstlane(v) * D;
        float acc = biasc;
#pragma unroll
        for (int k = 0; k < D; k++) acc = fmaf(hp[k], Wreg[k], acc);
        dstp[v * 32 + fl2] = __float2half_rn(acc);
    }
}

// ---------------------------------------------------------------- aggregate
// One pass covers features [FH*32, FH*32+32). 16-lane group handles 2
// consecutive nodes as one contiguous edge range [e0,e2) with split m.
// Lane fl gathers ONE uint (features {2fl,2fl+1}) from the 3.2 MB L2-resident
// half; a group's 16 lanes cover the 64B row exactly. em reads nontemporal
// so the gather half owns L2.
__global__ __launch_bounds__(256) void agg_kernel(const unsigned int* __restrict__ xwh,
                                                  const int* __restrict__ row_ptr,
                                                  const unsigned int* __restrict__ em,
                                                  const float* __restrict__ bl,
                                                  const float* __restrict__ pa,
                                                  const float* __restrict__ hraw_prev,
                                                  const float* __restrict__ bnsum_p,
                                                  const float* __restrict__ gamma_p,
                                                  const float* __restrict__ beta_p,
                                                  float* __restrict__ hpre,
                                                  float* __restrict__ bnsum_l,
                                                  int FH) {
    __shared__ float r1[32], r2[32];
    int tid = threadIdx.x, lane = tid & 63;
    int sub = tid >> 4;        // group slot within block (0..15)
    int fl = lane & 15;        // feature-pair index within the half
    int srcbase = lane & 48;   // group base lane for shfl
    if (tid < 32) { r1[tid] = 0.f; r2[tid] = 0.f; }
    __syncthreads();

    float al = pa[0];
    int c0 = FH * 32 + 2 * fl;             // global channel of this lane's pair
    float2 bias = ((const float2*)bl)[FH * 16 + fl];
    float sc0 = 0, sc1 = 0, sh0 = 0, sh1 = 0;
    if (hraw_prev) {
        bn_affine8(bnsum_p, gamma_p, beta_p, c0 + 0, sc0, sh0);
        bn_affine8(bnsum_p, gamma_p, beta_p, c0 + 1, sc1, sh1);
    }
    float t1_0 = 0, t1_1 = 0, t2_0 = 0, t2_1 = 0;

    int v0 = (blockIdx.x * 16 + sub) * 2;  // first node of this group
    if (v0 < N_NODES) {
        int2 e01 = *(const int2*)(row_ptr + v0);   // e0, m
        int e0 = e01.x, m = e01.y;
        int e2 = row_ptr[v0 + 2];
        float A0 = 0, A1 = 0, B0 = 0, B1 = 0;
        unsigned mo = (e0 + fl < e2) ? __builtin_nontemporal_load(em + e0 + fl) : 0u;
        for (int e = e0; e < e2; e += 16) {
            unsigned mo_nx =
                (e + 16 + fl < e2) ? __builtin_nontemporal_load(em + e + 16 + fl) : 0u;
            unsigned mj[16];
            unsigned q[16];
#pragma unroll
            for (int j = 0; j < 16; j++) {
                mj[j] = (unsigned)__shfl((int)mo, srcbase + j, 64);
                q[j] = xwh[(mj[j] >> 16) * 16 + fl];  // 4B gather, L2-resident half
            }
#pragma unroll
            for (int j = 0; j < 16; j++) {
                float w = unpack_w(mj[j]);
                bool isB = (e + j) >= m;
                float wa = isB ? 0.f : w;
                float wb = isB ? w : 0.f;
                float2 f = unpack_x2(q[j]);
                A0 = fmaf(wa, f.x, A0); A1 = fmaf(wa, f.y, A1);
                B0 = fmaf(wb, f.x, B0); B1 = fmaf(wb, f.y, B1);
            }
            mo = mo_nx;
        }
#pragma unroll
        for (int n = 0; n < 2; n++) {
            int v = v0 + n;
            float h0 = (n ? B0 : A0) + bias.x;
            float h1 = (n ? B1 : A1) + bias.y;
            h0 = h0 >= 0.f ? h0 : al * h0;
            h1 = h1 >= 0.f ? h1 : al * h1;
            if (hraw_prev) {
                float2 p01 = ntload_f2((const float2*)hraw_prev + v * 32 + FH * 16 + fl);
                h0 = fmaf(p01.x, sc0, h0 + sh0);
                h1 = fmaf(p01.y, sc1, h1 + sh1);
            }
            ntstore_f2((float2*)hpre + v * 32 + FH * 16 + fl, make_float2(h0, h1));
            t1_0 += h0; t1_1 += h1;
            t2_0 = fmaf(h0, h0, t2_0);
            t2_1 = fmaf(h1, h1, t2_1);
        }
    }
    // wave pre-reduce across the 4 sub-groups (same channels at lane & 15)
    t1_0 += __shfl_xor(t1_0, 16, 64); t1_0 += __shfl_xor(t1_0, 32, 64);
    t1_1 += __shfl_xor(t1_1, 16, 64); t1_1 += __shfl_xor(t1_1, 32, 64);
    t2_0 += __shfl_xor(t2_0, 16, 64); t2_0 += __shfl_xor(t2_0, 32, 64);
    t2_1 += __shfl_xor(t2_1, 16, 64); t2_1 += __shfl_xor(t2_1, 32, 64);
    if (lane < 16) {
        atomicAdd(&r1[2 * fl + 0], t1_0);
        atomicAdd(&r1[2 * fl + 1], t1_1);
        atomicAdd(&r2[2 * fl + 0], t2_0);
        atomicAdd(&r2[2 * fl + 1], t2_1);
    }
    __syncthreads();
    if (tid < 32) {
        float* myb = bnsum_l + (size_t)get_xcc() * BN_XSTRIDE;
        atomicAdd(&myb[FH * 32 + tid], r1[tid]);
        atomicAdd(&myb[D + FH * 32 + tid], r2[tid]);
    }
}

// ---------------------------------------------------------------- final BN apply
__global__ __launch_bounds__(256) void bnapply_kernel(const float* __restrict__ hpre,
                                                      const float* __restrict__ bnsum_p,
                                                      const float* __restrict__ gamma_p,
                                                      const float* __restrict__ beta_p,
                                                      float* __restrict__ out) {
    __shared__ float aff[2][D];
    int tid = threadIdx.x;
    if (tid < D) {
        float sc, sh;
        bn_affine8(bnsum_p, gamma_p, beta_p, tid, sc, sh);
        aff[0][tid] = sc;
        aff[1][tid] = sh;
    }
    __syncthreads();
    int i = blockIdx.x * blockDim.x + tid;
    int stride = gridDim.x * blockDim.x;
    const int NQ = N_NODES * D / 4;
    for (int j = i; j < NQ; j += stride) {
        float4 hv = ((const float4*)hpre)[j];
        int c = (j * 4) & 63;
        float4 o;
        o.x = fmaf(hv.x, aff[0][c + 0], aff[1][c + 0]);
        o.y = fmaf(hv.y, aff[0][c + 1], aff[1][c + 1]);
        o.z = fmaf(hv.z, aff[0][c + 2], aff[1][c + 2]);
        o.w = fmaf(hv.w, aff[0][c + 3], aff[1][c + 3]);
        ((float4*)out)[j] = o;
    }
}

// ---------------------------------------------------------------- launch
extern "C" void kernel_launch(void* const* d_in, const int* in_sizes, int n_in,
                              void* d_out, int out_size, void* d_ws, size_t ws_size,
                              hipStream_t stream) {
    const float* x     = (const float*)d_in[0];
    const int*   esrc  = (const int*)d_in[1];
    const int*   edst  = (const int*)d_in[2];
    const float* ew    = (const float*)d_in[3];
    const float* W     = (const float*)d_in[4];
    const float* b     = (const float*)d_in[5];
    const float* pa    = (const float*)d_in[6];
    const float* gamma = (const float*)d_in[7];
    const float* beta  = (const float*)d_in[8];
    float* out = (float*)d_out;

    char* ws = (char*)d_ws;
    size_t off = 0;
    auto alloc = [&](size_t bytes) -> char* {
        char* p = ws + off;
        off = (off + bytes + 255) & ~(size_t)255;
        return p;
    };
    int*            counts8  = (int*)alloc((size_t)NXCD * N_NODES * 4);
    int*            counts   = (int*)alloc((size_t)N_NODES * 4);
    int*            row_ptr  = (int*)alloc((size_t)(N_NODES + 1) * 4);
    int*            offs8    = (int*)alloc((size_t)NXCD * N_NODES * 4);
    int*            blocksum = (int*)alloc((size_t)NB_SCAN * 4);
    int*            blockoff = (int*)alloc((size_t)NB_SCAN * 4);
    unsigned short* rankx    = (unsigned short*)alloc((size_t)N_EDGES * 2);
    unsigned int*   em       = (unsigned int*)alloc((size_t)N_EDGES * 4);
    __half*         xw2      = (__half*)alloc((size_t)2 * N_NODES * 32 * 2);
    float*          hpre1    = (float*)alloc((size_t)N_NODES * D * 4);
    float*          bnsum8   = (float*)alloc((size_t)NXCD * BN_XSTRIDE * 4);

    init_kernel<<<512, 256, 0, stream>>>(counts8, bnsum8);
    count_kernel<<<2048, 256, 0, stream>>>(edst, counts8, rankx);
    scanA_kernel<<<NB_SCAN, 256, 0, stream>>>(counts8, counts, blocksum);
    scanB_kernel<<<1, 256, 0, stream>>>(blocksum, blockoff, row_ptr);
    scanC_kernel<<<NB_SCAN, 256, 0, stream>>>(counts, counts8, blockoff, row_ptr, offs8);
    fill_kernel<<<2048, 256, 0, stream>>>(esrc, edst, ew, rankx, offs8, em);

    // hpre storage: layer0 -> d_out, layer1 -> ws, layer2 -> d_out
    float* hbuf[L] = {out, hpre1, out};
    for (int i = 0; i < L; i++) {
        const float* hin = (i == 0) ? x : hbuf[i - 1];
        const float* bns = (i == 0) ? nullptr : bnsum8 + (i - 1) * 2 * D;
        const float* gmp = (i == 0) ? nullptr : gamma + (i - 1) * D;
        const float* btp = (i == 0) ? nullptr : beta + (i - 1) * D;
        gemm_kernel<<<1024, 256, 0, stream>>>(hin, bns, gmp, btp, W + (size_t)i * D * D, xw2);
        for (int FH = 0; FH < 2; FH++) {
            const unsigned int* xwh =
                (const unsigned int*)xw2 + (size_t)FH * N_NODES * 16;
            agg_kernel<<<AGG_BLOCKS, 256, 0, stream>>>(xwh, row_ptr, em,
                                                       b + i * D, pa + i,
                                                       (i == 0) ? nullptr : hbuf[i - 1],
                                                       bns, gmp, btp,
                                                       hbuf[i], bnsum8 + i * 2 * D, FH);
        }
    }
    bnapply_kernel<<<2048, 256, 0, stream>>>(hbuf[2], bnsum8 + 2 * 2 * D,
                                             gamma + 2 * D, beta + 2 * D, out);
}

// Round 12
// 242.525 us; speedup vs baseline: 1.0931x; 1.0931x over previous
//
#include <hip/hip_runtime.h>
#include <hip/hip_fp16.h>

#define N_NODES 50000
#define N_EDGES 1000000
#define D 64
#define L 3
#define BN_EPS 1e-5f
#define NB_SCAN ((N_NODES + 255) / 256)   // 196 blocks of 256
#define AGG_BLOCKS ((N_NODES + 31) / 32)  // 1563: 16 groups/block, 2 nodes/group
#define NXCD 8
#define BN_XSTRIDE (L * 2 * D)            // per-XCD bnsum replica stride (floats)

// ---------------------------------------------------------------- helpers
__device__ inline int get_xcc() {
    int x;
    asm volatile("s_getreg_b32 %0, hwreg(HW_REG_XCC_ID)" : "=s"(x));
    return x & (NXCD - 1);
}

// BN affine from per-XCD replicated sums.
__device__ inline void bn_affine8(const float* __restrict__ bnsum_l,
                                  const float* __restrict__ gamma,
                                  const float* __restrict__ beta,
                                  int c, float& sc, float& sh) {
    float s1 = 0.f, s2 = 0.f;
#pragma unroll
    for (int x = 0; x < NXCD; x++) {
        s1 += bnsum_l[(size_t)x * BN_XSTRIDE + c];
        s2 += bnsum_l[(size_t)x * BN_XSTRIDE + D + c];
    }
    float mean = s1 * (1.f / N_NODES);
    float var = fmaf(-mean, mean, s2 * (1.f / N_NODES));
    float inv = rsqrtf(var + BN_EPS);
    sc = gamma[c] * inv;
    sh = fmaf(-mean, sc, beta[c]);
}

__device__ inline float unpack_w(unsigned int m) {
    __half_raw hr;
    hr.x = (unsigned short)(m & 0xffffu);
    __half h = *reinterpret_cast<__half*>(&hr);
    return __half2float(h);
}

__device__ inline float2 unpack_x2(unsigned int q) {
    __half2 h2 = *reinterpret_cast<__half2*>(&q);
    return __half22float2(h2);
}

__device__ inline float2 ntload_f2(const float2* p) {
    unsigned long long u = __builtin_nontemporal_load((const unsigned long long*)p);
    float2 r;
    r.x = __uint_as_float((unsigned int)(u & 0xffffffffull));
    r.y = __uint_as_float((unsigned int)(u >> 32));
    return r;
}

__device__ inline void ntstore_f2(float2* p, float2 v) {
    unsigned long long u =
        ((unsigned long long)__float_as_uint(v.y) << 32) | (unsigned long long)__float_as_uint(v.x);
    __builtin_nontemporal_store(u, (unsigned long long*)p);
}

// ---------------------------------------------------------------- init
__global__ void init_kernel(int* __restrict__ counts8, float* __restrict__ bnsum8) {
    int i = blockIdx.x * blockDim.x + threadIdx.x;
    int stride = gridDim.x * blockDim.x;
    for (int j = i; j < NXCD * N_NODES; j += stride) counts8[j] = 0;
    for (int j = i; j < NXCD * BN_XSTRIDE; j += stride) bnsum8[j] = 0.f;
}

// ---------------------------------------------------------------- CSR build
// Per-XCD histograms: atomics stay local to one XCD's L2. Streaming inputs /
// outputs nontemporal so counts8 lines own the L2.
__global__ void count_kernel(const int* __restrict__ dst, int* __restrict__ counts8,
                             unsigned short* __restrict__ rankx) {
    int xcd = get_xcc();
    int* mycnt = counts8 + (size_t)xcd * N_NODES;
    int i = blockIdx.x * blockDim.x + threadIdx.x;
    int stride = gridDim.x * blockDim.x;
    for (int e = i; e < N_EDGES; e += stride) {
        int d = __builtin_nontemporal_load(dst + e);
        int r = atomicAdd(&mycnt[d], 1);
        __builtin_nontemporal_store((unsigned short)(r | (xcd << 13)), rankx + e);
    }
}

__global__ __launch_bounds__(256) void scanA_kernel(const int* __restrict__ counts8,
                                                    int* __restrict__ counts,
                                                    int* __restrict__ blocksum) {
    __shared__ int buf[256];
    int t = threadIdx.x, b = blockIdx.x;
    int i = b * 256 + t;
    int v = 0;
    if (i < N_NODES) {
#pragma unroll
        for (int x = 0; x < NXCD; x++) v += counts8[(size_t)x * N_NODES + i];
        counts[i] = v;
    }
    buf[t] = v;
    __syncthreads();
    for (int off = 128; off > 0; off >>= 1) {
        if (t < off) buf[t] += buf[t + off];
        __syncthreads();
    }
    if (t == 0) blocksum[b] = buf[0];
}

// phase C: computes its own block offset from blocksum (scanB eliminated),
// then local scan -> row_ptr + per-(xcd,node) scatter bases offs8.
__global__ __launch_bounds__(256) void scanC_kernel(const int* __restrict__ counts,
                                                    const int* __restrict__ counts8,
                                                    const int* __restrict__ blocksum,
                                                    int* __restrict__ row_ptr,
                                                    int* __restrict__ offs8) {
    __shared__ int buf[256];
    __shared__ int boff_s;
    int t = threadIdx.x, b = blockIdx.x;
    // exclusive offset of this block = sum of blocksum[j], j < b
    int bs = (t < NB_SCAN && t < b) ? blocksum[t] : 0;
    buf[t] = bs;
    __syncthreads();
    for (int off = 128; off > 0; off >>= 1) {
        if (t < off) buf[t] += buf[t + off];
        __syncthreads();
    }
    if (t == 0) boff_s = buf[0];
    __syncthreads();
    int boff = boff_s;
    int i = b * 256 + t;
    int v = (i < N_NODES) ? counts[i] : 0;
    __syncthreads();  // buf reuse
    buf[t] = v;
    __syncthreads();
    for (int off = 1; off < 256; off <<= 1) {
        int u = (t >= off) ? buf[t - off] : 0;
        __syncthreads();
        buf[t] += u;
        __syncthreads();
    }
    if (i < N_NODES) {
        int base = boff + buf[t] - v;
        row_ptr[i] = base;
#pragma unroll
        for (int x = 0; x < NXCD; x++) {
            offs8[(size_t)x * N_NODES + i] = base;
            base += counts8[(size_t)x * N_NODES + i];
        }
    }
    if (b == NB_SCAN - 1 && t == 255) row_ptr[N_NODES] = boff + buf[255];
}

// scatter edges into dst-sorted order; no atomics. em stores nontemporal
// (scattered 4B stores: avoid L2 write-allocate/RFO thrash).
__global__ void fill_kernel(const int* __restrict__ src, const int* __restrict__ dst,
                            const float* __restrict__ w,
                            const unsigned short* __restrict__ rankx,
                            const int* __restrict__ offs8,
                            unsigned int* __restrict__ em) {
    int i = blockIdx.x * blockDim.x + threadIdx.x;
    int stride = gridDim.x * blockDim.x;
    for (int e = i; e < N_EDGES; e += stride) {
        int d = __builtin_nontemporal_load(dst + e);
        unsigned rx = __builtin_nontemporal_load(rankx + e);
        int s = __builtin_nontemporal_load(src + e);
        float wf = __builtin_nontemporal_load(w + e);
        int p = offs8[(size_t)(rx >> 13) * N_NODES + d] + (int)(rx & 0x1fffu);
        __half h = __float2half_rn(wf);
        unsigned short wb = reinterpret_cast<__half_raw*>(&h)->x;
        __builtin_nontemporal_store(((unsigned int)s << 16) | (unsigned int)wb, em + p);
    }
}

// ---------------------------------------------------------------- GEMM
// xw[v][c] = sum_k (hraw[v][k]*scale[k]+shift[k]) * W[k][c], output fp16 [N][64].
__global__ __launch_bounds__(256) void gemm_kernel(const float* __restrict__ hraw,
                                                   const float* __restrict__ bnsum_p,
                                                   const float* __restrict__ gamma_p,
                                                   const float* __restrict__ beta_p,
                                                   const float* __restrict__ Wl,
                                                   __half* __restrict__ xw) {
    __shared__ float aff[2][D];
    int tid = threadIdx.x, lane = tid & 63, wave = tid >> 6;
    if (tid < D) {
        float sc = 1.f, sh = 0.f;
        if (bnsum_p) bn_affine8(bnsum_p, gamma_p, beta_p, tid, sc, sh);
        aff[0][tid] = sc;
        aff[1][tid] = sh;
    }
    __syncthreads();
    float Wreg[D];
    float biasc = 0.f;
#pragma unroll
    for (int k = 0; k < D; k++) {
        float wkc = Wl[k * D + lane];
        biasc = fmaf(aff[1][k], wkc, biasc);
        Wreg[k] = wkc * aff[0][k];
    }
    int gw = blockIdx.x * 4 + wave, nw = gridDim.x * 4;
    for (int v = gw; v < N_NODES; v += nw) {
        const float* hp = hraw + (size_t)__builtin_amdgcn_readfirstlane(v) * D;
        float acc = biasc;
#pragma unroll
        for (int k = 0; k < D; k++) acc = fmaf(hp[k], Wreg[k], acc);
        xw[v * D + lane] = __float2half_rn(acc);
    }
}

// ---------------------------------------------------------------- aggregate
// (r10-proven) 16-lane group handles 2 consecutive nodes as ONE contiguous
// edge range [e0,e2) with split m; predicated wa/wb routing; em prefetch.
// Lane fl owns features 4fl..4fl+3 (uint2 gather).
__global__ __launch_bounds__(256) void agg_kernel(const uint2* __restrict__ xw,
                                                  const int* __restrict__ row_ptr,
                                                  const unsigned int* __restrict__ em,
                                                  const float* __restrict__ bl,
                                                  const float* __restrict__ pa,
                                                  const float* __restrict__ hraw_prev,
                                                  const float* __restrict__ bnsum_p,
                                                  const float* __restrict__ gamma_p,
                                                  const float* __restrict__ beta_p,
                                                  float* __restrict__ hpre,
                                                  float* __restrict__ bnsum_l) {
    __shared__ float r1[D], r2[D];
    int tid = threadIdx.x, lane = tid & 63;
    int sub = tid >> 4;        // group slot within block (0..15)
    int fl = lane & 15;        // feature-quad index
    int srcbase = lane & 48;   // group base lane for shfl
    if (tid < D) { r1[tid] = 0.f; r2[tid] = 0.f; }
    __syncthreads();

    float al = pa[0];
    int c0 = 4 * fl;
    float4 bias = ((const float4*)bl)[fl];
    float sc0 = 0, sc1 = 0, sc2 = 0, sc3 = 0, sh0 = 0, sh1 = 0, sh2 = 0, sh3 = 0;
    if (hraw_prev) {
        bn_affine8(bnsum_p, gamma_p, beta_p, c0 + 0, sc0, sh0);
        bn_affine8(bnsum_p, gamma_p, beta_p, c0 + 1, sc1, sh1);
        bn_affine8(bnsum_p, gamma_p, beta_p, c0 + 2, sc2, sh2);
        bn_affine8(bnsum_p, gamma_p, beta_p, c0 + 3, sc3, sh3);
    }
    float t1_0 = 0, t1_1 = 0, t1_2 = 0, t1_3 = 0;
    float t2_0 = 0, t2_1 = 0, t2_2 = 0, t2_3 = 0;

    int v0 = (blockIdx.x * 16 + sub) * 2;  // first node of this group
    if (v0 < N_NODES) {
        int2 e01 = *(const int2*)(row_ptr + v0);   // e0, m (v0 even -> aligned)
        int e0 = e01.x, m = e01.y;
        int e2 = row_ptr[v0 + 2];
        float A0 = 0, A1 = 0, A2 = 0, A3 = 0, B0 = 0, B1 = 0, B2 = 0, B3 = 0;
        unsigned mo = (e0 + fl < e2) ? __builtin_nontemporal_load(em + e0 + fl) : 0u;
        for (int e = e0; e < e2; e += 16) {
            unsigned mo_nx =
                (e + 16 + fl < e2) ? __builtin_nontemporal_load(em + e + 16 + fl) : 0u;
            unsigned mj[16];
            uint2 q[16];
#pragma unroll
            for (int j = 0; j < 16; j++) {
                mj[j] = (unsigned)__shfl((int)mo, srcbase + j, 64);
                q[j] = xw[(mj[j] >> 16) * 16 + fl];  // 8B gather: features 4fl..4fl+3
            }
#pragma unroll
            for (int j = 0; j < 16; j++) {
                float w = unpack_w(mj[j]);
                bool isB = (e + j) >= m;
                float wa = isB ? 0.f : w;
                float wb = isB ? w : 0.f;
                float2 f01 = unpack_x2(q[j].x);
                float2 f23 = unpack_x2(q[j].y);
                A0 = fmaf(wa, f01.x, A0); A1 = fmaf(wa, f01.y, A1);
                A2 = fmaf(wa, f23.x, A2); A3 = fmaf(wa, f23.y, A3);
                B0 = fmaf(wb, f01.x, B0); B1 = fmaf(wb, f01.y, B1);
                B2 = fmaf(wb, f23.x, B2); B3 = fmaf(wb, f23.y, B3);
            }
            mo = mo_nx;
        }
#pragma unroll
        for (int n = 0; n < 2; n++) {
            int v = v0 + n;
            float h0 = (n ? B0 : A0) + bias.x;
            float h1 = (n ? B1 : A1) + bias.y;
            float h2 = (n ? B2 : A2) + bias.z;
            float h3 = (n ? B3 : A3) + bias.w;
            h0 = h0 >= 0.f ? h0 : al * h0;
            h1 = h1 >= 0.f ? h1 : al * h1;
            h2 = h2 >= 0.f ? h2 : al * h2;
            h3 = h3 >= 0.f ? h3 : al * h3;
            if (hraw_prev) {
                float2 p01 = ntload_f2((const float2*)hraw_prev + v * 32 + 2 * fl);
                float2 p23 = ntload_f2((const float2*)hraw_prev + v * 32 + 2 * fl + 1);
                h0 = fmaf(p01.x, sc0, h0 + sh0);
                h1 = fmaf(p01.y, sc1, h1 + sh1);
                h2 = fmaf(p23.x, sc2, h2 + sh2);
                h3 = fmaf(p23.y, sc3, h3 + sh3);
            }
            ntstore_f2((float2*)hpre + v * 32 + 2 * fl, make_float2(h0, h1));
            ntstore_f2((float2*)hpre + v * 32 + 2 * fl + 1, make_float2(h2, h3));
            t1_0 += h0; t1_1 += h1; t1_2 += h2; t1_3 += h3;
            t2_0 = fmaf(h0, h0, t2_0);
            t2_1 = fmaf(h1, h1, t2_1);
            t2_2 = fmaf(h2, h2, t2_2);
            t2_3 = fmaf(h3, h3, t2_3);
        }
    }
    // wave pre-reduce across the 4 sub-groups (same channels at lane & 15)
    t1_0 += __shfl_xor(t1_0, 16, 64); t1_0 += __shfl_xor(t1_0, 32, 64);
    t1_1 += __shfl_xor(t1_1, 16, 64); t1_1 += __shfl_xor(t1_1, 32, 64);
    t1_2 += __shfl_xor(t1_2, 16, 64); t1_2 += __shfl_xor(t1_2, 32, 64);
    t1_3 += __shfl_xor(t1_3, 16, 64); t1_3 += __shfl_xor(t1_3, 32, 64);
    t2_0 += __shfl_xor(t2_0, 16, 64); t2_0 += __shfl_xor(t2_0, 32, 64);
    t2_1 += __shfl_xor(t2_1, 16, 64); t2_1 += __shfl_xor(t2_1, 32, 64);
    t2_2 += __shfl_xor(t2_2, 16, 64); t2_2 += __shfl_xor(t2_2, 32, 64);
    t2_3 += __shfl_xor(t2_3, 16, 64); t2_3 += __shfl_xor(t2_3, 32, 64);
    if (lane < 16) {
        atomicAdd(&r1[c0 + 0], t1_0);
        atomicAdd(&r1[c0 + 1], t1_1);
        atomicAdd(&r1[c0 + 2], t1_2);
        atomicAdd(&r1[c0 + 3], t1_3);
        atomicAdd(&r2[c0 + 0], t2_0);
        atomicAdd(&r2[c0 + 1], t2_1);
        atomicAdd(&r2[c0 + 2], t2_2);
        atomicAdd(&r2[c0 + 3], t2_3);
    }
    __syncthreads();
    if (tid < D) {
        float* myb = bnsum_l + (size_t)get_xcc() * BN_XSTRIDE;
        atomicAdd(&myb[tid], r1[tid]);
        atomicAdd(&myb[D + tid], r2[tid]);
    }
}

// ---------------------------------------------------------------- final BN apply
__global__ __launch_bounds__(256) void bnapply_kernel(const float* __restrict__ hpre,
                                                      const float* __restrict__ bnsum_p,
                                                      const float* __restrict__ gamma_p,
                                                      const float* __restrict__ beta_p,
                                                      float* __restrict__ out) {
    __shared__ float aff[2][D];
    int tid = threadIdx.x;
    if (tid < D) {
        float sc, sh;
        bn_affine8(bnsum_p, gamma_p, beta_p, tid, sc, sh);
        aff[0][tid] = sc;
        aff[1][tid] = sh;
    }
    __syncthreads();
    int i = blockIdx.x * blockDim.x + tid;
    int stride = gridDim.x * blockDim.x;
    const int NQ = N_NODES * D / 4;
    for (int j = i; j < NQ; j += stride) {
        float4 hv = ((const float4*)hpre)[j];
        int c = (j * 4) & 63;
        float4 o;
        o.x = fmaf(hv.x, aff[0][c + 0], aff[1][c + 0]);
        o.y = fmaf(hv.y, aff[0][c + 1], aff[1][c + 1]);
        o.z = fmaf(hv.z, aff[0][c + 2], aff[1][c + 2]);
        o.w = fmaf(hv.w, aff[0][c + 3], aff[1][c + 3]);
        ((float4*)out)[j] = o;
    }
}

// ---------------------------------------------------------------- launch
extern "C" void kernel_launch(void* const* d_in, const int* in_sizes, int n_in,
                              void* d_out, int out_size, void* d_ws, size_t ws_size,
                              hipStream_t stream) {
    const float* x     = (const float*)d_in[0];
    const int*   esrc  = (const int*)d_in[1];
    const int*   edst  = (const int*)d_in[2];
    const float* ew    = (const float*)d_in[3];
    const float* W     = (const float*)d_in[4];
    const float* b     = (const float*)d_in[5];
    const float* pa    = (const float*)d_in[6];
    const float* gamma = (const float*)d_in[7];
    const float* beta  = (const float*)d_in[8];
    float* out = (float*)d_out;

    char* ws = (char*)d_ws;
    size_t off = 0;
    auto alloc = [&](size_t bytes) -> char* {
        char* p = ws + off;
        off = (off + bytes + 255) & ~(size_t)255;
        return p;
    };
    int*            counts8  = (int*)alloc((size_t)NXCD * N_NODES * 4);
    int*            counts   = (int*)alloc((size_t)N_NODES * 4);
    int*            row_ptr  = (int*)alloc((size_t)(N_NODES + 1) * 4);
    int*            offs8    = (int*)alloc((size_t)NXCD * N_NODES * 4);
    int*            blocksum = (int*)alloc((size_t)NB_SCAN * 4);
    unsigned short* rankx    = (unsigned short*)alloc((size_t)N_EDGES * 2);
    unsigned int*   em       = (unsigned int*)alloc((size_t)N_EDGES * 4);
    __half*         xw       = (__half*)alloc((size_t)N_NODES * D * 2);
    float*          hpre1    = (float*)alloc((size_t)N_NODES * D * 4);
    float*          bnsum8   = (float*)alloc((size_t)NXCD * BN_XSTRIDE * 4);

    init_kernel<<<512, 256, 0, stream>>>(counts8, bnsum8);
    count_kernel<<<2048, 256, 0, stream>>>(edst, counts8, rankx);
    scanA_kernel<<<NB_SCAN, 256, 0, stream>>>(counts8, counts, blocksum);
    scanC_kernel<<<NB_SCAN, 256, 0, stream>>>(counts, counts8, blocksum, row_ptr, offs8);
    fill_kernel<<<2048, 256, 0, stream>>>(esrc, edst, ew, rankx, offs8, em);

    // hpre storage: layer0 -> d_out, layer1 -> ws, layer2 -> d_out
    float* hbuf[L] = {out, hpre1, out};
    for (int i = 0; i < L; i++) {
        const float* hin = (i == 0) ? x : hbuf[i - 1];
        const float* bns = (i == 0) ? nullptr : bnsum8 + (i - 1) * 2 * D;
        const float* gmp = (i == 0) ? nullptr : gamma + (i - 1) * D;
        const float* btp = (i == 0) ? nullptr : beta + (i - 1) * D;
        gemm_kernel<<<1024, 256, 0, stream>>>(hin, bns, gmp, btp, W + (size_t)i * D * D, xw);
        agg_kernel<<<AGG_BLOCKS, 256, 0, stream>>>((const uint2*)xw, row_ptr, em,
                                                   b + i * D, pa + i,
                                                   (i == 0) ? nullptr : hbuf[i - 1],
                                                   bns, gmp, btp,
                                                   hbuf[i], bnsum8 + i * 2 * D);
    }
    bnapply_kernel<<<2048, 256, 0, stream>>>(hbuf[2], bnsum8 + 2 * 2 * D,
                                             gamma + 2 * D, beta + 2 * D, out);
}

// Round 13
// 226.046 us; speedup vs baseline: 1.1728x; 1.0729x over previous
//
#include <hip/hip_runtime.h>
#include <hip/hip_fp16.h>

#define N_NODES 50000
#define N_EDGES 1000000
#define D 64
#define L 3
#define BN_EPS 1e-5f
#define NB_SCAN ((N_NODES + 255) / 256)   // 196 blocks of 256
#define AGG_BLOCKS ((N_NODES + 31) / 32)  // 1563: 16 groups/block, 2 nodes/group
#define NXCD 8
#define BN_XSTRIDE (L * 2 * D)            // per-XCD bnsum replica stride (floats)

// ---------------------------------------------------------------- helpers
__device__ inline int get_xcc() {
    int x;
    asm volatile("s_getreg_b32 %0, hwreg(HW_REG_XCC_ID)" : "=s"(x));
    return x & (NXCD - 1);
}

// BN affine from per-XCD replicated sums.
__device__ inline void bn_affine8(const float* __restrict__ bnsum_l,
                                  const float* __restrict__ gamma,
                                  const float* __restrict__ beta,
                                  int c, float& sc, float& sh) {
    float s1 = 0.f, s2 = 0.f;
#pragma unroll
    for (int x = 0; x < NXCD; x++) {
        s1 += bnsum_l[(size_t)x * BN_XSTRIDE + c];
        s2 += bnsum_l[(size_t)x * BN_XSTRIDE + D + c];
    }
    float mean = s1 * (1.f / N_NODES);
    float var = fmaf(-mean, mean, s2 * (1.f / N_NODES));
    float inv = rsqrtf(var + BN_EPS);
    sc = gamma[c] * inv;
    sh = fmaf(-mean, sc, beta[c]);
}

__device__ inline float unpack_w(unsigned int m) {
    __half_raw hr;
    hr.x = (unsigned short)(m & 0xffffu);
    __half h = *reinterpret_cast<__half*>(&hr);
    return __half2float(h);
}

__device__ inline float2 unpack_x2(unsigned int q) {
    __half2 h2 = *reinterpret_cast<__half2*>(&q);
    return __half22float2(h2);
}

__device__ inline float2 ntload_f2(const float2* p) {
    unsigned long long u = __builtin_nontemporal_load((const unsigned long long*)p);
    float2 r;
    r.x = __uint_as_float((unsigned int)(u & 0xffffffffull));
    r.y = __uint_as_float((unsigned int)(u >> 32));
    return r;
}

__device__ inline void ntstore_f2(float2* p, float2 v) {
    unsigned long long u =
        ((unsigned long long)__float_as_uint(v.y) << 32) | (unsigned long long)__float_as_uint(v.x);
    __builtin_nontemporal_store(u, (unsigned long long*)p);
}

// ---------------------------------------------------------------- init
__global__ void init_kernel(int* __restrict__ counts8, float* __restrict__ bnsum8) {
    int i = blockIdx.x * blockDim.x + threadIdx.x;
    int stride = gridDim.x * blockDim.x;
    for (int j = i; j < NXCD * N_NODES; j += stride) counts8[j] = 0;
    for (int j = i; j < NXCD * BN_XSTRIDE; j += stride) bnsum8[j] = 0.f;
}

// ---------------------------------------------------------------- CSR build
// Per-XCD histograms: atomics stay local to one XCD's L2 (no cross-XCD
// cacheline ping-pong). rankx = local rank | (xcd << 13).  (r10-proven: plain
// loads/stores — NT scatter regressed in r12.)
__global__ void count_kernel(const int* __restrict__ dst, int* __restrict__ counts8,
                             unsigned short* __restrict__ rankx) {
    int xcd = get_xcc();
    int* mycnt = counts8 + (size_t)xcd * N_NODES;
    int i = blockIdx.x * blockDim.x + threadIdx.x;
    int stride = gridDim.x * blockDim.x;
    for (int e = i; e < N_EDGES; e += stride) {
        int r = atomicAdd(&mycnt[dst[e]], 1);
        rankx[e] = (unsigned short)(r | (xcd << 13));
    }
}

__global__ __launch_bounds__(256) void scanA_kernel(const int* __restrict__ counts8,
                                                    int* __restrict__ counts,
                                                    int* __restrict__ blocksum) {
    __shared__ int buf[256];
    int t = threadIdx.x, b = blockIdx.x;
    int i = b * 256 + t;
    int v = 0;
    if (i < N_NODES) {
#pragma unroll
        for (int x = 0; x < NXCD; x++) v += counts8[(size_t)x * N_NODES + i];
        counts[i] = v;
    }
    buf[t] = v;
    __syncthreads();
    for (int off = 128; off > 0; off >>= 1) {
        if (t < off) buf[t] += buf[t + off];
        __syncthreads();
    }
    if (t == 0) blocksum[b] = buf[0];
}

// phase C: computes its own block offset from blocksum (scanB eliminated),
// then local scan -> row_ptr + per-(xcd,node) scatter bases offs8.
__global__ __launch_bounds__(256) void scanC_kernel(const int* __restrict__ counts,
                                                    const int* __restrict__ counts8,
                                                    const int* __restrict__ blocksum,
                                                    int* __restrict__ row_ptr,
                                                    int* __restrict__ offs8) {
    __shared__ int buf[256];
    __shared__ int boff_s;
    int t = threadIdx.x, b = blockIdx.x;
    // exclusive offset of this block = sum of blocksum[j], j < b
    int bs = (t < NB_SCAN && t < b) ? blocksum[t] : 0;
    buf[t] = bs;
    __syncthreads();
    for (int off = 128; off > 0; off >>= 1) {
        if (t < off) buf[t] += buf[t + off];
        __syncthreads();
    }
    if (t == 0) boff_s = buf[0];
    __syncthreads();
    int boff = boff_s;
    int i = b * 256 + t;
    int v = (i < N_NODES) ? counts[i] : 0;
    __syncthreads();  // buf reuse
    buf[t] = v;
    __syncthreads();
    for (int off = 1; off < 256; off <<= 1) {
        int u = (t >= off) ? buf[t - off] : 0;
        __syncthreads();
        buf[t] += u;
        __syncthreads();
    }
    if (i < N_NODES) {
        int base = boff + buf[t] - v;
        row_ptr[i] = base;
#pragma unroll
        for (int x = 0; x < NXCD; x++) {
            offs8[(size_t)x * N_NODES + i] = base;
            base += counts8[(size_t)x * N_NODES + i];
        }
    }
    if (b == NB_SCAN - 1 && t == 255) row_ptr[N_NODES] = boff + buf[255];
}

// scatter edges into dst-sorted order; no atomics (rank+xcd precomputed).
// Plain stores: L2 write-back merges the scattered 4B stores (r10-proven).
__global__ void fill_kernel(const int* __restrict__ src, const int* __restrict__ dst,
                            const float* __restrict__ w,
                            const unsigned short* __restrict__ rankx,
                            const int* __restrict__ offs8,
                            unsigned int* __restrict__ em) {
    int i = blockIdx.x * blockDim.x + threadIdx.x;
    int stride = gridDim.x * blockDim.x;
    for (int e = i; e < N_EDGES; e += stride) {
        int d = dst[e];
        unsigned rx = rankx[e];
        int p = offs8[(size_t)(rx >> 13) * N_NODES + d] + (int)(rx & 0x1fffu);
        __half h = __float2half_rn(w[e]);
        unsigned short wb = reinterpret_cast<__half_raw*>(&h)->x;
        em[p] = ((unsigned int)src[e] << 16) | (unsigned int)wb;
    }
}

// ---------------------------------------------------------------- GEMM
// xw[v][c] = sum_k (hraw[v][k]*scale[k]+shift[k]) * W[k][c], output fp16 [N][64].
__global__ __launch_bounds__(256) void gemm_kernel(const float* __restrict__ hraw,
                                                   const float* __restrict__ bnsum_p,
                                                   const float* __restrict__ gamma_p,
                                                   const float* __restrict__ beta_p,
                                                   const float* __restrict__ Wl,
                                                   __half* __restrict__ xw) {
    __shared__ float aff[2][D];
    int tid = threadIdx.x, lane = tid & 63, wave = tid >> 6;
    if (tid < D) {
        float sc = 1.f, sh = 0.f;
        if (bnsum_p) bn_affine8(bnsum_p, gamma_p, beta_p, tid, sc, sh);
        aff[0][tid] = sc;
        aff[1][tid] = sh;
    }
    __syncthreads();
    float Wreg[D];
    float biasc = 0.f;
#pragma unroll
    for (int k = 0; k < D; k++) {
        float wkc = Wl[k * D + lane];
        biasc = fmaf(aff[1][k], wkc, biasc);
        Wreg[k] = wkc * aff[0][k];
    }
    int gw = blockIdx.x * 4 + wave, nw = gridDim.x * 4;
    for (int v = gw; v < N_NODES; v += nw) {
        const float* hp = hraw + (size_t)__builtin_amdgcn_readfirstlane(v) * D;
        float acc = biasc;
#pragma unroll
        for (int k = 0; k < D; k++) acc = fmaf(hp[k], Wreg[k], acc);
        xw[v * D + lane] = __float2half_rn(acc);
    }
}

// ---------------------------------------------------------------- aggregate
// (r10-proven) 16-lane group handles 2 consecutive nodes as ONE contiguous
// edge range [e0,e2) with split m; predicated wa/wb routing; em prefetch.
// Lane fl owns features 4fl..4fl+3 (uint2 gather).
__global__ __launch_bounds__(256) void agg_kernel(const uint2* __restrict__ xw,
                                                  const int* __restrict__ row_ptr,
                                                  const unsigned int* __restrict__ em,
                                                  const float* __restrict__ bl,
                                                  const float* __restrict__ pa,
                                                  const float* __restrict__ hraw_prev,
                                                  const float* __restrict__ bnsum_p,
                                                  const float* __restrict__ gamma_p,
                                                  const float* __restrict__ beta_p,
                                                  float* __restrict__ hpre,
                                                  float* __restrict__ bnsum_l) {
    __shared__ float r1[D], r2[D];
    int tid = threadIdx.x, lane = tid & 63;
    int sub = tid >> 4;        // group slot within block (0..15)
    int fl = lane & 15;        // feature-quad index
    int srcbase = lane & 48;   // group base lane for shfl
    if (tid < D) { r1[tid] = 0.f; r2[tid] = 0.f; }
    __syncthreads();

    float al = pa[0];
    int c0 = 4 * fl;
    float4 bias = ((const float4*)bl)[fl];
    float sc0 = 0, sc1 = 0, sc2 = 0, sc3 = 0, sh0 = 0, sh1 = 0, sh2 = 0, sh3 = 0;
    if (hraw_prev) {
        bn_affine8(bnsum_p, gamma_p, beta_p, c0 + 0, sc0, sh0);
        bn_affine8(bnsum_p, gamma_p, beta_p, c0 + 1, sc1, sh1);
        bn_affine8(bnsum_p, gamma_p, beta_p, c0 + 2, sc2, sh2);
        bn_affine8(bnsum_p, gamma_p, beta_p, c0 + 3, sc3, sh3);
    }
    float t1_0 = 0, t1_1 = 0, t1_2 = 0, t1_3 = 0;
    float t2_0 = 0, t2_1 = 0, t2_2 = 0, t2_3 = 0;

    int v0 = (blockIdx.x * 16 + sub) * 2;  // first node of this group
    if (v0 < N_NODES) {
        int2 e01 = *(const int2*)(row_ptr + v0);   // e0, m (v0 even -> aligned)
        int e0 = e01.x, m = e01.y;
        int e2 = row_ptr[v0 + 2];
        float A0 = 0, A1 = 0, A2 = 0, A3 = 0, B0 = 0, B1 = 0, B2 = 0, B3 = 0;
        unsigned mo = (e0 + fl < e2) ? __builtin_nontemporal_load(em + e0 + fl) : 0u;
        for (int e = e0; e < e2; e += 16) {
            unsigned mo_nx =
                (e + 16 + fl < e2) ? __builtin_nontemporal_load(em + e + 16 + fl) : 0u;
            unsigned mj[16];
            uint2 q[16];
#pragma unroll
            for (int j = 0; j < 16; j++) {
                mj[j] = (unsigned)__shfl((int)mo, srcbase + j, 64);
                q[j] = xw[(mj[j] >> 16) * 16 + fl];  // 8B gather: features 4fl..4fl+3
            }
#pragma unroll
            for (int j = 0; j < 16; j++) {
                float w = unpack_w(mj[j]);
                bool isB = (e + j) >= m;
                float wa = isB ? 0.f : w;
                float wb = isB ? w : 0.f;
                float2 f01 = unpack_x2(q[j].x);
                float2 f23 = unpack_x2(q[j].y);
                A0 = fmaf(wa, f01.x, A0); A1 = fmaf(wa, f01.y, A1);
                A2 = fmaf(wa, f23.x, A2); A3 = fmaf(wa, f23.y, A3);
                B0 = fmaf(wb, f01.x, B0); B1 = fmaf(wb, f01.y, B1);
                B2 = fmaf(wb, f23.x, B2); B3 = fmaf(wb, f23.y, B3);
            }
            mo = mo_nx;
        }
#pragma unroll
        for (int n = 0; n < 2; n++) {
            int v = v0 + n;
            float h0 = (n ? B0 : A0) + bias.x;
            float h1 = (n ? B1 : A1) + bias.y;
            float h2 = (n ? B2 : A2) + bias.z;
            float h3 = (n ? B3 : A3) + bias.w;
            h0 = h0 >= 0.f ? h0 : al * h0;
            h1 = h1 >= 0.f ? h1 : al * h1;
            h2 = h2 >= 0.f ? h2 : al * h2;
            h3 = h3 >= 0.f ? h3 : al * h3;
            if (hraw_prev) {
                float2 p01 = ntload_f2((const float2*)hraw_prev + v * 32 + 2 * fl);
                float2 p23 = ntload_f2((const float2*)hraw_prev + v * 32 + 2 * fl + 1);
                h0 = fmaf(p01.x, sc0, h0 + sh0);
                h1 = fmaf(p01.y, sc1, h1 + sh1);
                h2 = fmaf(p23.x, sc2, h2 + sh2);
                h3 = fmaf(p23.y, sc3, h3 + sh3);
            }
            ntstore_f2((float2*)hpre + v * 32 + 2 * fl, make_float2(h0, h1));
            ntstore_f2((float2*)hpre + v * 32 + 2 * fl + 1, make_float2(h2, h3));
            t1_0 += h0; t1_1 += h1; t1_2 += h2; t1_3 += h3;
            t2_0 = fmaf(h0, h0, t2_0);
            t2_1 = fmaf(h1, h1, t2_1);
            t2_2 = fmaf(h2, h2, t2_2);
            t2_3 = fmaf(h3, h3, t2_3);
        }
    }
    // wave pre-reduce across the 4 sub-groups (same channels at lane & 15)
    t1_0 += __shfl_xor(t1_0, 16, 64); t1_0 += __shfl_xor(t1_0, 32, 64);
    t1_1 += __shfl_xor(t1_1, 16, 64); t1_1 += __shfl_xor(t1_1, 32, 64);
    t1_2 += __shfl_xor(t1_2, 16, 64); t1_2 += __shfl_xor(t1_2, 32, 64);
    t1_3 += __shfl_xor(t1_3, 16, 64); t1_3 += __shfl_xor(t1_3, 32, 64);
    t2_0 += __shfl_xor(t2_0, 16, 64); t2_0 += __shfl_xor(t2_0, 32, 64);
    t2_1 += __shfl_xor(t2_1, 16, 64); t2_1 += __shfl_xor(t2_1, 32, 64);
    t2_2 += __shfl_xor(t2_2, 16, 64); t2_2 += __shfl_xor(t2_2, 32, 64);
    t2_3 += __shfl_xor(t2_3, 16, 64); t2_3 += __shfl_xor(t2_3, 32, 64);
    if (lane < 16) {
        atomicAdd(&r1[c0 + 0], t1_0);
        atomicAdd(&r1[c0 + 1], t1_1);
        atomicAdd(&r1[c0 + 2], t1_2);
        atomicAdd(&r1[c0 + 3], t1_3);
        atomicAdd(&r2[c0 + 0], t2_0);
        atomicAdd(&r2[c0 + 1], t2_1);
        atomicAdd(&r2[c0 + 2], t2_2);
        atomicAdd(&r2[c0 + 3], t2_3);
    }
    __syncthreads();
    if (tid < D) {
        float* myb = bnsum_l + (size_t)get_xcc() * BN_XSTRIDE;
        atomicAdd(&myb[tid], r1[tid]);
        atomicAdd(&myb[D + tid], r2[tid]);
    }
}

// ---------------------------------------------------------------- final BN apply
__global__ __launch_bounds__(256) void bnapply_kernel(const float* __restrict__ hpre,
                                                      const float* __restrict__ bnsum_p,
                                                      const float* __restrict__ gamma_p,
                                                      const float* __restrict__ beta_p,
                                                      float* __restrict__ out) {
    __shared__ float aff[2][D];
    int tid = threadIdx.x;
    if (tid < D) {
        float sc, sh;
        bn_affine8(bnsum_p, gamma_p, beta_p, tid, sc, sh);
        aff[0][tid] = sc;
        aff[1][tid] = sh;
    }
    __syncthreads();
    int i = blockIdx.x * blockDim.x + tid;
    int stride = gridDim.x * blockDim.x;
    const int NQ = N_NODES * D / 4;
    for (int j = i; j < NQ; j += stride) {
        float4 hv = ((const float4*)hpre)[j];
        int c = (j * 4) & 63;
        float4 o;
        o.x = fmaf(hv.x, aff[0][c + 0], aff[1][c + 0]);
        o.y = fmaf(hv.y, aff[0][c + 1], aff[1][c + 1]);
        o.z = fmaf(hv.z, aff[0][c + 2], aff[1][c + 2]);
        o.w = fmaf(hv.w, aff[0][c + 3], aff[1][c + 3]);
        ((float4*)out)[j] = o;
    }
}

// ---------------------------------------------------------------- launch
extern "C" void kernel_launch(void* const* d_in, const int* in_sizes, int n_in,
                              void* d_out, int out_size, void* d_ws, size_t ws_size,
                              hipStream_t stream) {
    const float* x     = (const float*)d_in[0];
    const int*   esrc  = (const int*)d_in[1];
    const int*   edst  = (const int*)d_in[2];
    const float* ew    = (const float*)d_in[3];
    const float* W     = (const float*)d_in[4];
    const float* b     = (const float*)d_in[5];
    const float* pa    = (const float*)d_in[6];
    const float* gamma = (const float*)d_in[7];
    const float* beta  = (const float*)d_in[8];
    float* out = (float*)d_out;

    char* ws = (char*)d_ws;
    size_t off = 0;
    auto alloc = [&](size_t bytes) -> char* {
        char* p = ws + off;
        off = (off + bytes + 255) & ~(size_t)255;
        return p;
    };
    int*            counts8  = (int*)alloc((size_t)NXCD * N_NODES * 4);
    int*            counts   = (int*)alloc((size_t)N_NODES * 4);
    int*            row_ptr  = (int*)alloc((size_t)(N_NODES + 1) * 4);
    int*            offs8    = (int*)alloc((size_t)NXCD * N_NODES * 4);
    int*            blocksum = (int*)alloc((size_t)NB_SCAN * 4);
    unsigned short* rankx    = (unsigned short*)alloc((size_t)N_EDGES * 2);
    unsigned int*   em       = (unsigned int*)alloc((size_t)N_EDGES * 4);
    __half*         xw       = (__half*)alloc((size_t)N_NODES * D * 2);
    float*          hpre1    = (float*)alloc((size_t)N_NODES * D * 4);
    float*          bnsum8   = (float*)alloc((size_t)NXCD * BN_XSTRIDE * 4);

    init_kernel<<<512, 256, 0, stream>>>(counts8, bnsum8);
    count_kernel<<<2048, 256, 0, stream>>>(edst, counts8, rankx);
    scanA_kernel<<<NB_SCAN, 256, 0, stream>>>(counts8, counts, blocksum);
    scanC_kernel<<<NB_SCAN, 256, 0, stream>>>(counts, counts8, blocksum, row_ptr, offs8);
    fill_kernel<<<2048, 256, 0, stream>>>(esrc, edst, ew, rankx, offs8, em);

    // hpre storage: layer0 -> d_out, layer1 -> ws, layer2 -> d_out
    float* hbuf[L] = {out, hpre1, out};
    for (int i = 0; i < L; i++) {
        const float* hin = (i == 0) ? x : hbuf[i - 1];
        const float* bns = (i == 0) ? nullptr : bnsum8 + (i - 1) * 2 * D;
        const float* gmp = (i == 0) ? nullptr : gamma + (i - 1) * D;
        const float* btp = (i == 0) ? nullptr : beta + (i - 1) * D;
        gemm_kernel<<<1024, 256, 0, stream>>>(hin, bns, gmp, btp, W + (size_t)i * D * D, xw);
        agg_kernel<<<AGG_BLOCKS, 256, 0, stream>>>((const uint2*)xw, row_ptr, em,
                                                   b + i * D, pa + i,
                                                   (i == 0) ? nullptr : hbuf[i - 1],
                                                   bns, gmp, btp,
                                                   hbuf[i], bnsum8 + i * 2 * D);
    }
    bnapply_kernel<<<2048, 256, 0, stream>>>(hbuf[2], bnsum8 + 2 * 2 * D,
                                             gamma + 2 * D, beta + 2 * D, out);
}